// Round 5
// baseline (260.429 us; speedup 1.0000x reference)
//
#include <hip/hip_runtime.h>
#include <math.h>

#define HIDDEN 128
#define NBLOCKS 256
#define NTHREADS 1024
#define BMAP_WORDS 6272                    // 200704 bits >= 200000 nodes
#define NHW (NBLOCKS * (NTHREADS / 64) * 2)   // 8192 half-waves
#define BATCH_STRIDE (NHW * 8)             // 65536 rows per sweep

// ---------------------------------------------------------------------------
// Prep kernel (1 block, 1024 thr): scatter visited -> global bitmap (atomicOr,
// duplicate-safe); fc=[x;X[s];X[p]]; q=fc@Wq; qk=(Wk@q)/sqrt(128) -> global.
// ---------------------------------------------------------------------------
__global__ __launch_bounds__(1024) void prep_kernel(
    const float* __restrict__ X, const float* __restrict__ x,
    const float* __restrict__ Wq, const float* __restrict__ Wk,
    const int* __restrict__ visited, int nv,
    const int* __restrict__ startp, const int* __restrict__ prevp,
    unsigned* __restrict__ bmap, float* __restrict__ qk)
{
    __shared__ float fc[384];
    __shared__ float qpart[8][HIDDEN];
    __shared__ float qv[HIDDEN];
    const int tid = threadIdx.x;

    for (int i = tid; i < nv; i += 1024) {
        const int v = visited[i];
        atomicOr(&bmap[v >> 5], 1u << (v & 31));
    }
    if (tid < 128)       fc[tid] = x[tid];
    else if (tid < 256)  fc[tid] = X[(size_t)startp[0] * HIDDEN + (tid - 128)];
    else if (tid < 384)  fc[tid] = X[(size_t)prevp[0]  * HIDDEN + (tid - 256)];
    __syncthreads();

    const int col = tid & (HIDDEN - 1);
    const int seg = tid >> 7;
    {
        float acc = 0.f;
        const int m0 = seg * 48;
        #pragma unroll 8
        for (int m = 0; m < 48; ++m)
            acc += fc[m0 + m] * Wq[(size_t)(m0 + m) * HIDDEN + col];
        qpart[seg][col] = acc;
    }
    __syncthreads();
    if (tid < HIDDEN) {
        float s = 0.f;
        #pragma unroll
        for (int k = 0; k < 8; ++k) s += qpart[k][tid];
        qv[tid] = s;
    }
    __syncthreads();
    {
        const int sub = tid & 31;
        const int hw32 = tid >> 5;
        const float4 qv4 = *(const float4*)(&qv[sub << 2]);
        for (int row = hw32; row < HIDDEN; row += 32) {
            const float4 wk4 = *(const float4*)(Wk + (size_t)row * HIDDEN + (sub << 2));
            float p = wk4.x * qv4.x + wk4.y * qv4.y + wk4.z * qv4.z + wk4.w * qv4.w;
            #pragma unroll
            for (int off = 16; off >= 1; off >>= 1)
                p += __shfl_xor(p, off, 64);
            if (sub == 0) qk[row] = p * 0.08838834764831845f;
        }
    }
}

// ---------------------------------------------------------------------------
// Main kernel: batch-8 streaming online softmax. Half-wave processes 8
// consecutive rows/iter (wave reads 16 rows = 8 KB contiguous). Mask bits for
// the 8 rows are one bitmap-word broadcast; u = p - bit (global +1 cancels).
// Last-block finish combines partials and applies Wv, Wo.
// ---------------------------------------------------------------------------
__global__ __launch_bounds__(NTHREADS, 4) void main_kernel(
    const float* __restrict__ X, const unsigned* __restrict__ bmap,
    const float* __restrict__ qk,
    const float* __restrict__ Wv, const float* __restrict__ Wo,
    float* __restrict__ Mb, float* __restrict__ Sb, float* __restrict__ Gb,
    unsigned* __restrict__ counter,
    float* __restrict__ out, int n)
{
    __shared__ float m_arr[32], s_arr[32];
    __shared__ float g_all[32 * HIDDEN];   // 16 KB (aliased as e/red in finish)
    __shared__ float qpart[8][HIDDEN];     // 4 KB (finish GEMVs)
    __shared__ float pv[HIDDEN], hv[HIDDEN];
    __shared__ bool  is_last;

    const int tid  = threadIdx.x;
    const int lane = tid & 63;
    const int sub  = lane & 31;
    const int half = (lane >> 5) & 1;
    const int vhw  = (blockIdx.x * (NTHREADS >> 6) + (tid >> 6)) * 2 + half;

    const float4 qkv = *(const float4*)(qk + (sub << 2));

    float m = -INFINITY, s = 0.f;
    float g0 = 0.f, g1 = 0.f, g2 = 0.f, g3 = 0.f;

    int base = vhw * 8;
    for (; base + 7 < n; base += BATCH_STRIDE) {
        const float* rp = X + (size_t)base * HIDDEN + (sub << 2);
        float4 xv[8];
        #pragma unroll
        for (int i = 0; i < 8; ++i)
            xv[i] = *(const float4*)(rp + i * HIDDEN);
        const unsigned mw  = bmap[base >> 5];
        const int      boff = base & 31;    // always 0/8/16/24: 8 bits in-word
        float p[8];
        #pragma unroll
        for (int i = 0; i < 8; ++i)
            p[i] = xv[i].x * qkv.x + xv[i].y * qkv.y + xv[i].z * qkv.z + xv[i].w * qkv.w;
        #pragma unroll
        for (int off = 16; off >= 1; off >>= 1) {
            #pragma unroll
            for (int i = 0; i < 8; ++i)
                p[i] += __shfl_xor(p[i], off, 64);
        }
        float u[8];
        #pragma unroll
        for (int i = 0; i < 8; ++i)
            u[i] = p[i] - (float)((mw >> (boff + i)) & 1u);
        const float bm = fmaxf(fmaxf(fmaxf(u[0], u[1]), fmaxf(u[2], u[3])),
                               fmaxf(fmaxf(u[4], u[5]), fmaxf(u[6], u[7])));
        const float mn    = fmaxf(m, bm);
        const float scale = __expf(m - mn);   // exp(-inf)=0 on first batch
        float w[8];
        #pragma unroll
        for (int i = 0; i < 8; ++i) w[i] = __expf(u[i] - mn);
        s  = s * scale + (((w[0] + w[1]) + (w[2] + w[3])) + ((w[4] + w[5]) + (w[6] + w[7])));
        float a0 = 0.f, a1 = 0.f, a2 = 0.f, a3 = 0.f;
        #pragma unroll
        for (int i = 0; i < 8; ++i) {
            a0 += w[i] * xv[i].x;  a1 += w[i] * xv[i].y;
            a2 += w[i] * xv[i].z;  a3 += w[i] * xv[i].w;
        }
        g0 = g0 * scale + a0;  g1 = g1 * scale + a1;
        g2 = g2 * scale + a2;  g3 = g3 * scale + a3;
        m  = mn;
    }
    if (base < n) {                          // remainder: 1..7 valid rows
        const int cnt = n - base;
        const float* rp = X + (size_t)base * HIDDEN + (sub << 2);
        float4 xv[8];
        #pragma unroll
        for (int i = 0; i < 8; ++i)
            xv[i] = (i < cnt) ? *(const float4*)(rp + i * HIDDEN)
                              : make_float4(0.f, 0.f, 0.f, 0.f);
        const unsigned mw  = bmap[base >> 5];
        const int      boff = base & 31;
        float p[8];
        #pragma unroll
        for (int i = 0; i < 8; ++i)
            p[i] = xv[i].x * qkv.x + xv[i].y * qkv.y + xv[i].z * qkv.z + xv[i].w * qkv.w;
        #pragma unroll
        for (int off = 16; off >= 1; off >>= 1) {
            #pragma unroll
            for (int i = 0; i < 8; ++i)
                p[i] += __shfl_xor(p[i], off, 64);
        }
        float u[8];
        #pragma unroll
        for (int i = 0; i < 8; ++i)
            u[i] = (i < cnt) ? (p[i] - (float)((mw >> (boff + i)) & 1u)) : -1e30f;
        const float bm = fmaxf(fmaxf(fmaxf(u[0], u[1]), fmaxf(u[2], u[3])),
                               fmaxf(fmaxf(u[4], u[5]), fmaxf(u[6], u[7])));
        const float mn    = fmaxf(m, bm);    // m finite (>=3 full batches done)
        const float scale = __expf(m - mn);
        float w[8];
        #pragma unroll
        for (int i = 0; i < 8; ++i) w[i] = __expf(u[i] - mn);
        s  = s * scale + (((w[0] + w[1]) + (w[2] + w[3])) + ((w[4] + w[5]) + (w[6] + w[7])));
        float a0 = 0.f, a1 = 0.f, a2 = 0.f, a3 = 0.f;
        #pragma unroll
        for (int i = 0; i < 8; ++i) {
            a0 += w[i] * xv[i].x;  a1 += w[i] * xv[i].y;
            a2 += w[i] * xv[i].z;  a3 += w[i] * xv[i].w;
        }
        g0 = g0 * scale + a0;  g1 = g1 * scale + a1;
        g2 = g2 * scale + a2;  g3 = g3 * scale + a3;
        m  = mn;
    }

    // ---------------- block combine -> partial ----------------
    const int hw = tid >> 5;
    *(float4*)(&g_all[hw * HIDDEN + (sub << 2)]) = make_float4(g0, g1, g2, g3);
    if (sub == 0) { m_arr[hw] = m; s_arr[hw] = s; }
    __syncthreads();

    float mbv = m_arr[0];
    #pragma unroll
    for (int h = 1; h < 32; ++h) mbv = fmaxf(mbv, m_arr[h]);

    if (tid < HIDDEN) {
        float G = 0.f;
        #pragma unroll 4
        for (int h = 0; h < 32; ++h)
            G += g_all[h * HIDDEN + tid] * __expf(m_arr[h] - mbv);
        Gb[(size_t)blockIdx.x * HIDDEN + tid] = G;
    } else if (tid == HIDDEN) {
        float S = 0.f;
        #pragma unroll
        for (int h = 0; h < 32; ++h) S += s_arr[h] * __expf(m_arr[h] - mbv);
        Sb[blockIdx.x] = S;
        Mb[blockIdx.x] = mbv;
    }

    // ---------------- last-block-done handoff ----------------
    __threadfence();
    __syncthreads();
    if (tid == 0) {
        const unsigned prev = atomicAdd(counter, 1u);
        is_last = (prev == (unsigned)(NBLOCKS - 1));
    }
    __syncthreads();
    if (!is_last) return;
    __threadfence();

    // ---------------- finish (one block) ----------------
    float* e   = g_all;
    float* red = g_all + 1024;

    const float mt = (tid < NBLOCKS) ? Mb[tid] : -INFINITY;
    red[tid] = mt;
    __syncthreads();
    for (int st = 512; st >= 1; st >>= 1) {
        if (tid < st) red[tid] = fmaxf(red[tid], red[tid + st]);
        __syncthreads();
    }
    const float M = red[0];
    __syncthreads();

    float ls = 0.f;
    if (tid < NBLOCKS) { const float eb = __expf(mt - M); e[tid] = eb; ls = Sb[tid] * eb; }
    red[tid] = ls;
    __syncthreads();
    for (int st = 512; st >= 1; st >>= 1) {
        if (tid < st) red[tid] += red[tid + st];
        __syncthreads();
    }
    const float S = red[0];
    __syncthreads();

    const int col = tid & (HIDDEN - 1);
    const int seg = tid >> 7;
    {
        float acc = 0.f;
        const int b0 = seg * (NBLOCKS / 8);
        #pragma unroll 8
        for (int b = 0; b < NBLOCKS / 8; ++b)
            acc += Gb[(size_t)(b0 + b) * HIDDEN + col] * e[b0 + b];
        qpart[seg][col] = acc;
    }
    __syncthreads();
    if (tid < HIDDEN) {
        float G = 0.f;
        #pragma unroll
        for (int k = 0; k < 8; ++k) G += qpart[k][tid];
        pv[tid] = G / S;
    }
    __syncthreads();
    {
        float acc = 0.f;
        const int m0 = seg * 16;
        #pragma unroll
        for (int mm = 0; mm < 16; ++mm)
            acc += pv[m0 + mm] * Wv[(size_t)(m0 + mm) * HIDDEN + col];
        qpart[seg][col] = acc;
    }
    __syncthreads();
    if (tid < HIDDEN) {
        float h = 0.f;
        #pragma unroll
        for (int k = 0; k < 8; ++k) h += qpart[k][tid];
        hv[tid] = h;
    }
    __syncthreads();
    {
        float acc = 0.f;
        const int m0 = seg * 16;
        #pragma unroll
        for (int mm = 0; mm < 16; ++mm)
            acc += hv[m0 + mm] * Wo[(size_t)(m0 + mm) * HIDDEN + col];
        qpart[seg][col] = acc;
    }
    __syncthreads();
    if (tid < HIDDEN) {
        float o = 0.f;
        #pragma unroll
        for (int k = 0; k < 8; ++k) o += qpart[k][tid];
        out[tid] = o;
    }
}

// ---------------------------------------------------------------------------
extern "C" void kernel_launch(void* const* d_in, const int* in_sizes, int n_in,
                              void* d_out, int out_size, void* d_ws, size_t ws_size,
                              hipStream_t stream)
{
    const float* X       = (const float*)d_in[0];
    const float* x       = (const float*)d_in[1];
    const float* Wq      = (const float*)d_in[2];
    const float* Wk      = (const float*)d_in[3];
    const float* Wv      = (const float*)d_in[4];
    const float* Wo      = (const float*)d_in[5];
    const int*   visited = (const int*)d_in[6];
    const int*   startp  = (const int*)d_in[7];
    const int*   prevp   = (const int*)d_in[8];

    const int n  = in_sizes[0] / HIDDEN;   // 200000
    const int nv = in_sizes[6];            // 1024

    // ws layout (32-bit words): [bitmap 6272][counter 1][pad 3][qk 128]
    //                           [Mb 256][Sb 256][Gb 256*128]
    unsigned* bmap    = (unsigned*)d_ws;
    unsigned* counter = bmap + BMAP_WORDS;
    float*    qk      = (float*)(bmap + BMAP_WORDS + 4);   // 16B-aligned
    float*    Mb      = qk + HIDDEN;
    float*    Sb      = Mb + NBLOCKS;
    float*    Gb      = Sb + NBLOCKS;

    hipMemsetAsync(bmap, 0, (BMAP_WORDS + 1) * sizeof(unsigned), stream);
    prep_kernel<<<1, 1024, 0, stream>>>(X, x, Wq, Wk, visited, nv, startp, prevp, bmap, qk);
    main_kernel<<<NBLOCKS, NTHREADS, 0, stream>>>(
        X, bmap, qk, Wv, Wo, Mb, Sb, Gb, counter, (float*)d_out, n);
}

// Round 6
// 258.853 us; speedup vs baseline: 1.0061x; 1.0061x over previous
//
#include <hip/hip_runtime.h>
#include <math.h>

#define HIDDEN 128
#define NBLOCKS 256
#define NTHREADS 1024
#define BMAP_WORDS 6272                    // 200704 bits >= 200000 nodes
#define NHW (NBLOCKS * (NTHREADS / 64) * 2)   // 8192 half-waves
#define BATCH_STRIDE (NHW * 8)             // 65536 rows per sweep

// NOTE (R3-R5 post-mortem): __launch_bounds__(1024, K) for K>=2 on this
// toolchain acts like CUDA's min-BLOCKS-per-SM: K=4 with 16-wave blocks
// implies 16 waves/SIMD -> VGPR cap 32 -> compiler serializes all loads
// (VGPR_Count=32/36, VALUBusy 3.5%, 120us). NEVER pass a second arg with
// 1024-thread blocks.

// ---------------------------------------------------------------------------
// Prep kernel (1 block, 1024 thr): scatter visited -> global bitmap (atomicOr,
// duplicate-safe); fc=[x;X[s];X[p]]; q=fc@Wq; qk=(Wk@q)/sqrt(128) -> global.
// ---------------------------------------------------------------------------
__global__ __launch_bounds__(1024) void prep_kernel(
    const float* __restrict__ X, const float* __restrict__ x,
    const float* __restrict__ Wq, const float* __restrict__ Wk,
    const int* __restrict__ visited, int nv,
    const int* __restrict__ startp, const int* __restrict__ prevp,
    unsigned* __restrict__ bmap, float* __restrict__ qk)
{
    __shared__ float fc[384];
    __shared__ float qpart[8][HIDDEN];
    __shared__ float qv[HIDDEN];
    const int tid = threadIdx.x;

    for (int i = tid; i < nv; i += 1024) {
        const int v = visited[i];
        atomicOr(&bmap[v >> 5], 1u << (v & 31));
    }
    if (tid < 128)       fc[tid] = x[tid];
    else if (tid < 256)  fc[tid] = X[(size_t)startp[0] * HIDDEN + (tid - 128)];
    else if (tid < 384)  fc[tid] = X[(size_t)prevp[0]  * HIDDEN + (tid - 256)];
    __syncthreads();

    const int col = tid & (HIDDEN - 1);
    const int seg = tid >> 7;
    {
        float acc = 0.f;
        const int m0 = seg * 48;
        #pragma unroll 8
        for (int m = 0; m < 48; ++m)
            acc += fc[m0 + m] * Wq[(size_t)(m0 + m) * HIDDEN + col];
        qpart[seg][col] = acc;
    }
    __syncthreads();
    if (tid < HIDDEN) {
        float s = 0.f;
        #pragma unroll
        for (int k = 0; k < 8; ++k) s += qpart[k][tid];
        qv[tid] = s;
    }
    __syncthreads();
    {
        const int sub = tid & 31;
        const int hw32 = tid >> 5;
        const float4 qv4 = *(const float4*)(&qv[sub << 2]);
        for (int row = hw32; row < HIDDEN; row += 32) {
            const float4 wk4 = *(const float4*)(Wk + (size_t)row * HIDDEN + (sub << 2));
            float p = wk4.x * qv4.x + wk4.y * qv4.y + wk4.z * qv4.z + wk4.w * qv4.w;
            #pragma unroll
            for (int off = 16; off >= 1; off >>= 1)
                p += __shfl_xor(p, off, 64);
            if (sub == 0) qk[row] = p * 0.08838834764831845f;
        }
    }
}

// ---------------------------------------------------------------------------
// Main kernel: batch-8 streaming online softmax. Half-wave processes 8
// consecutive rows/iter (wave reads 16 rows = 8 KB contiguous). Mask bits for
// the 8 rows are one bitmap-word broadcast; u = p - bit (global +1 cancels).
// Last-block finish combines partials and applies Wv, Wo.
// ---------------------------------------------------------------------------
__global__ __launch_bounds__(NTHREADS) void main_kernel(
    const float* __restrict__ X, const unsigned* __restrict__ bmap,
    const float* __restrict__ qk,
    const float* __restrict__ Wv, const float* __restrict__ Wo,
    float* __restrict__ Mb, float* __restrict__ Sb, float* __restrict__ Gb,
    unsigned* __restrict__ counter,
    float* __restrict__ out, int n)
{
    __shared__ float m_arr[32], s_arr[32];
    __shared__ float g_all[32 * HIDDEN];   // 16 KB (aliased as e/red in finish)
    __shared__ float qpart[8][HIDDEN];     // 4 KB (finish GEMVs)
    __shared__ float pv[HIDDEN], hv[HIDDEN];
    __shared__ bool  is_last;

    const int tid  = threadIdx.x;
    const int lane = tid & 63;
    const int sub  = lane & 31;
    const int half = (lane >> 5) & 1;
    const int vhw  = (blockIdx.x * (NTHREADS >> 6) + (tid >> 6)) * 2 + half;

    const float4 qkv = *(const float4*)(qk + (sub << 2));

    float m = -INFINITY, s = 0.f;
    float g0 = 0.f, g1 = 0.f, g2 = 0.f, g3 = 0.f;

    int base = vhw * 8;
    for (; base + 7 < n; base += BATCH_STRIDE) {
        const float* rp = X + (size_t)base * HIDDEN + (sub << 2);
        float4 xv[8];
        #pragma unroll
        for (int i = 0; i < 8; ++i)
            xv[i] = *(const float4*)(rp + i * HIDDEN);
        const unsigned mw  = bmap[base >> 5];
        const int      boff = base & 31;    // always 0/8/16/24: 8 bits in-word
        float p[8];
        #pragma unroll
        for (int i = 0; i < 8; ++i)
            p[i] = xv[i].x * qkv.x + xv[i].y * qkv.y + xv[i].z * qkv.z + xv[i].w * qkv.w;
        #pragma unroll
        for (int off = 16; off >= 1; off >>= 1) {
            #pragma unroll
            for (int i = 0; i < 8; ++i)
                p[i] += __shfl_xor(p[i], off, 64);
        }
        float u[8];
        #pragma unroll
        for (int i = 0; i < 8; ++i)
            u[i] = p[i] - (float)((mw >> (boff + i)) & 1u);
        const float bm = fmaxf(fmaxf(fmaxf(u[0], u[1]), fmaxf(u[2], u[3])),
                               fmaxf(fmaxf(u[4], u[5]), fmaxf(u[6], u[7])));
        const float mn    = fmaxf(m, bm);
        const float scale = __expf(m - mn);   // exp(-inf)=0 on first batch
        float w[8];
        #pragma unroll
        for (int i = 0; i < 8; ++i) w[i] = __expf(u[i] - mn);
        s  = s * scale + (((w[0] + w[1]) + (w[2] + w[3])) + ((w[4] + w[5]) + (w[6] + w[7])));
        float a0 = 0.f, a1 = 0.f, a2 = 0.f, a3 = 0.f;
        #pragma unroll
        for (int i = 0; i < 8; ++i) {
            a0 += w[i] * xv[i].x;  a1 += w[i] * xv[i].y;
            a2 += w[i] * xv[i].z;  a3 += w[i] * xv[i].w;
        }
        g0 = g0 * scale + a0;  g1 = g1 * scale + a1;
        g2 = g2 * scale + a2;  g3 = g3 * scale + a3;
        m  = mn;
    }
    if (base < n) {                          // remainder: 1..7 valid rows
        const int cnt = n - base;
        const float* rp = X + (size_t)base * HIDDEN + (sub << 2);
        float4 xv[8];
        #pragma unroll
        for (int i = 0; i < 8; ++i)
            xv[i] = (i < cnt) ? *(const float4*)(rp + i * HIDDEN)
                              : make_float4(0.f, 0.f, 0.f, 0.f);
        const unsigned mw  = bmap[base >> 5];
        const int      boff = base & 31;
        float p[8];
        #pragma unroll
        for (int i = 0; i < 8; ++i)
            p[i] = xv[i].x * qkv.x + xv[i].y * qkv.y + xv[i].z * qkv.z + xv[i].w * qkv.w;
        #pragma unroll
        for (int off = 16; off >= 1; off >>= 1) {
            #pragma unroll
            for (int i = 0; i < 8; ++i)
                p[i] += __shfl_xor(p[i], off, 64);
        }
        float u[8];
        #pragma unroll
        for (int i = 0; i < 8; ++i)
            u[i] = (i < cnt) ? (p[i] - (float)((mw >> (boff + i)) & 1u)) : -1e30f;
        const float bm = fmaxf(fmaxf(fmaxf(u[0], u[1]), fmaxf(u[2], u[3])),
                               fmaxf(fmaxf(u[4], u[5]), fmaxf(u[6], u[7])));
        const float mn    = fmaxf(m, bm);    // m finite (>=3 full batches done)
        const float scale = __expf(m - mn);
        float w[8];
        #pragma unroll
        for (int i = 0; i < 8; ++i) w[i] = __expf(u[i] - mn);
        s  = s * scale + (((w[0] + w[1]) + (w[2] + w[3])) + ((w[4] + w[5]) + (w[6] + w[7])));
        float a0 = 0.f, a1 = 0.f, a2 = 0.f, a3 = 0.f;
        #pragma unroll
        for (int i = 0; i < 8; ++i) {
            a0 += w[i] * xv[i].x;  a1 += w[i] * xv[i].y;
            a2 += w[i] * xv[i].z;  a3 += w[i] * xv[i].w;
        }
        g0 = g0 * scale + a0;  g1 = g1 * scale + a1;
        g2 = g2 * scale + a2;  g3 = g3 * scale + a3;
        m  = mn;
    }

    // ---------------- block combine -> partial ----------------
    const int hw = tid >> 5;
    *(float4*)(&g_all[hw * HIDDEN + (sub << 2)]) = make_float4(g0, g1, g2, g3);
    if (sub == 0) { m_arr[hw] = m; s_arr[hw] = s; }
    __syncthreads();

    float mbv = m_arr[0];
    #pragma unroll
    for (int h = 1; h < 32; ++h) mbv = fmaxf(mbv, m_arr[h]);

    if (tid < HIDDEN) {
        float G = 0.f;
        #pragma unroll 4
        for (int h = 0; h < 32; ++h)
            G += g_all[h * HIDDEN + tid] * __expf(m_arr[h] - mbv);
        Gb[(size_t)blockIdx.x * HIDDEN + tid] = G;
    } else if (tid == HIDDEN) {
        float S = 0.f;
        #pragma unroll
        for (int h = 0; h < 32; ++h) S += s_arr[h] * __expf(m_arr[h] - mbv);
        Sb[blockIdx.x] = S;
        Mb[blockIdx.x] = mbv;
    }

    // ---------------- last-block-done handoff ----------------
    __threadfence();
    __syncthreads();
    if (tid == 0) {
        const unsigned prev = atomicAdd(counter, 1u);
        is_last = (prev == (unsigned)(NBLOCKS - 1));
    }
    __syncthreads();
    if (!is_last) return;
    __threadfence();

    // ---------------- finish (one block) ----------------
    float* e   = g_all;
    float* red = g_all + 1024;

    const float mt = (tid < NBLOCKS) ? Mb[tid] : -INFINITY;
    red[tid] = mt;
    __syncthreads();
    for (int st = 512; st >= 1; st >>= 1) {
        if (tid < st) red[tid] = fmaxf(red[tid], red[tid + st]);
        __syncthreads();
    }
    const float M = red[0];
    __syncthreads();

    float ls = 0.f;
    if (tid < NBLOCKS) { const float eb = __expf(mt - M); e[tid] = eb; ls = Sb[tid] * eb; }
    red[tid] = ls;
    __syncthreads();
    for (int st = 512; st >= 1; st >>= 1) {
        if (tid < st) red[tid] += red[tid + st];
        __syncthreads();
    }
    const float S = red[0];
    __syncthreads();

    const int col = tid & (HIDDEN - 1);
    const int seg = tid >> 7;
    {
        float acc = 0.f;
        const int b0 = seg * (NBLOCKS / 8);
        #pragma unroll 8
        for (int b = 0; b < NBLOCKS / 8; ++b)
            acc += Gb[(size_t)(b0 + b) * HIDDEN + col] * e[b0 + b];
        qpart[seg][col] = acc;
    }
    __syncthreads();
    if (tid < HIDDEN) {
        float G = 0.f;
        #pragma unroll
        for (int k = 0; k < 8; ++k) G += qpart[k][tid];
        pv[tid] = G / S;
    }
    __syncthreads();
    {
        float acc = 0.f;
        const int m0 = seg * 16;
        #pragma unroll
        for (int mm = 0; mm < 16; ++mm)
            acc += pv[m0 + mm] * Wv[(size_t)(m0 + mm) * HIDDEN + col];
        qpart[seg][col] = acc;
    }
    __syncthreads();
    if (tid < HIDDEN) {
        float h = 0.f;
        #pragma unroll
        for (int k = 0; k < 8; ++k) h += qpart[k][tid];
        hv[tid] = h;
    }
    __syncthreads();
    {
        float acc = 0.f;
        const int m0 = seg * 16;
        #pragma unroll
        for (int mm = 0; mm < 16; ++mm)
            acc += hv[m0 + mm] * Wo[(size_t)(m0 + mm) * HIDDEN + col];
        qpart[seg][col] = acc;
    }
    __syncthreads();
    if (tid < HIDDEN) {
        float o = 0.f;
        #pragma unroll
        for (int k = 0; k < 8; ++k) o += qpart[k][tid];
        out[tid] = o;
    }
}

// ---------------------------------------------------------------------------
extern "C" void kernel_launch(void* const* d_in, const int* in_sizes, int n_in,
                              void* d_out, int out_size, void* d_ws, size_t ws_size,
                              hipStream_t stream)
{
    const float* X       = (const float*)d_in[0];
    const float* x       = (const float*)d_in[1];
    const float* Wq      = (const float*)d_in[2];
    const float* Wk      = (const float*)d_in[3];
    const float* Wv      = (const float*)d_in[4];
    const float* Wo      = (const float*)d_in[5];
    const int*   visited = (const int*)d_in[6];
    const int*   startp  = (const int*)d_in[7];
    const int*   prevp   = (const int*)d_in[8];

    const int n  = in_sizes[0] / HIDDEN;   // 200000
    const int nv = in_sizes[6];            // 1024

    // ws layout (32-bit words): [bitmap 6272][counter 1][pad 3][qk 128]
    //                           [Mb 256][Sb 256][Gb 256*128]
    unsigned* bmap    = (unsigned*)d_ws;
    unsigned* counter = bmap + BMAP_WORDS;
    float*    qk      = (float*)(bmap + BMAP_WORDS + 4);   // 16B-aligned
    float*    Mb      = qk + HIDDEN;
    float*    Sb      = Mb + NBLOCKS;
    float*    Gb      = Sb + NBLOCKS;

    hipMemsetAsync(bmap, 0, (BMAP_WORDS + 1) * sizeof(unsigned), stream);
    prep_kernel<<<1, 1024, 0, stream>>>(X, x, Wq, Wk, visited, nv, startp, prevp, bmap, qk);
    main_kernel<<<NBLOCKS, NTHREADS, 0, stream>>>(
        X, bmap, qk, Wv, Wo, Mb, Sb, Gb, counter, (float*)d_out, n);
}